// Round 7
// baseline (1032.916 us; speedup 1.0000x reference)
//
#include <hip/hip_runtime.h>
#include <hip/hip_fp16.h>

#define B_ 256
#define T_ 200
#define H_ 256
#define G3 768            // 3*H
#define NV 50001          // V+1
#define NFRAG 48          // 6 col-tiles x 8 k-tiles per thread
#define WELEM 196608      // 512 threads * NFRAG * 8 f16 per matrix

typedef __attribute__((ext_vector_type(8))) _Float16 f16x8;
typedef __attribute__((ext_vector_type(4))) float f32x4;

__device__ __forceinline__ float sigmoidf_(float x) {
  return 1.f / (1.f + __expf(-x));
}
__device__ __forceinline__ float tanhf_(float x) {
  float ax = fabsf(x);
  float e = __expf(-2.f * ax);
  float t = (1.f - e) / (1.f + e);
  return copysignf(t, x);
}

// Pre-pack both fp32 [256 x 768] weights into per-thread MFMA B-fragments:
// thread slot s=w*64+l, frag f=nt*8+kt, elem j holds w[k][col],
// k = kt*32 + (l>>4)*8 + j, col = w*96 + nt*16 + (l&15).
__global__ __launch_bounds__(256) void pack_w(
    const float* __restrict__ wih, const float* __restrict__ whh,
    __half* __restrict__ out) {
  int idx = blockIdx.x * 256 + threadIdx.x;   // 0 .. 2*WELEM-1
  int m = idx / WELEM;
  int r = idx - m * WELEM;
  int j = r & 7;
  int f = (r >> 3) % NFRAG;
  int s = r / (NFRAG * 8);
  int nt = f >> 3, kt = f & 7;
  int w = s >> 6, l = s & 63;
  int k = kt * 32 + ((l >> 4) & 3) * 8 + j;
  int col = w * 96 + nt * 16 + (l & 15);
  const float* src = m ? whh : wih;
  out[idx] = (__half)src[(size_t)k * G3 + col];
}

// Load this thread's 48 B-fragments (768 B). NO asm pinning — R5/R6's
// per-scalar "+a" pin is the prime numerics suspect. Plain loads; the RA
// may keep these in VGPR/AGPR (unified file) or re-load from L2.
__device__ __forceinline__ void load_w_frag(const __half* __restrict__ wp,
                                            int tid, uint4 Bv[NFRAG]) {
  const uint4* src = (const uint4*)wp + (size_t)tid * NFRAG;
#pragma unroll
  for (int f = 0; f < NFRAG; ++f) Bv[f] = src[f];
}

__device__ __forceinline__ f32x4 mfma16(f16x8 a, uint4 b, f32x4 c) {
  return __builtin_amdgcn_mfma_f32_16x16x32_f16(
      a, __builtin_bit_cast(f16x8, b), c, 0, 0, 0);
}

// K1: gates_x[b,t,col] = emb[ids[b,t]] . w_ih[:,col] + b_ih[col], fp16 out.
// One wg per batch row; 16 tokens per MFMA iteration.
__global__ __launch_bounds__(512)
__attribute__((amdgpu_waves_per_eu(2, 2)))
void gates_kernel(
    const int* __restrict__ ids, const int* __restrict__ lens,
    const float* __restrict__ emb, const __half* __restrict__ wih_p,
    const float* __restrict__ b_ih, __half* __restrict__ gates) {
  __shared__ __align__(16) __half At[16][264];   // 16 tokens x 256 K, pad 8
  __shared__ __align__(16) __half Ot[16][G3];    // 16 tokens x 768 cols
  __shared__ int ids_s[16];
  const int tid = threadIdx.x;
  const int b = blockIdx.x;
  const int l = tid & 63, w = tid >> 6;

  uint4 Bv[NFRAG];
  load_w_frag(wih_p, tid, Bv);

  float bias[6];
#pragma unroll
  for (int nt = 0; nt < 6; ++nt) bias[nt] = b_ih[w * 96 + nt * 16 + (l & 15)];

  const int len = lens[b];
  const int id0 = ids[(size_t)b * T_];

  for (int t0 = 0; t0 < len; t0 += 16) {
    if (tid < 16) {
      ids_s[tid] = (t0 + tid < len) ? ids[(size_t)b * T_ + t0 + tid] : id0;
    }
    __syncthreads();
    {  // stage A-tile: thread covers row tid>>5, K-segment (tid&31)*8
      int row = tid >> 5, seg = tid & 31;
      const float* er = emb + (size_t)ids_s[row] * H_ + seg * 8;
      float4 e0 = *(const float4*)er;
      float4 e1 = *(const float4*)(er + 4);
      union { uint4 u; _Float16 h[8]; } pk;
      pk.h[0] = (_Float16)e0.x; pk.h[1] = (_Float16)e0.y;
      pk.h[2] = (_Float16)e0.z; pk.h[3] = (_Float16)e0.w;
      pk.h[4] = (_Float16)e1.x; pk.h[5] = (_Float16)e1.y;
      pk.h[6] = (_Float16)e1.z; pk.h[7] = (_Float16)e1.w;
      *(uint4*)&At[row][seg * 8] = pk.u;
    }
    __syncthreads();
    f32x4 acc[6];
#pragma unroll
    for (int nt = 0; nt < 6; ++nt) acc[nt] = (f32x4){0.f, 0.f, 0.f, 0.f};
#pragma unroll
    for (int kt = 0; kt < 8; ++kt) {
      f16x8 A = *(const f16x8*)&At[l & 15][kt * 32 + ((l >> 4) & 3) * 8];
#pragma unroll
      for (int nt = 0; nt < 6; ++nt) acc[nt] = mfma16(A, Bv[nt * 8 + kt], acc[nt]);
    }
#pragma unroll
    for (int nt = 0; nt < 6; ++nt) {
      int col = w * 96 + nt * 16 + (l & 15);
      int r0 = ((l >> 4) & 3) * 4;
      Ot[r0 + 0][col] = (__half)(acc[nt].x + bias[nt]);
      Ot[r0 + 1][col] = (__half)(acc[nt].y + bias[nt]);
      Ot[r0 + 2][col] = (__half)(acc[nt].z + bias[nt]);
      Ot[r0 + 3][col] = (__half)(acc[nt].w + bias[nt]);
    }
    __syncthreads();
    {  // coalesced flush: thread covers row tid>>5, 24 f16 at (tid&31)*24
      int row = tid >> 5, seg = tid & 31;
      if (t0 + row < len) {
        const uint4* s = (const uint4*)&Ot[row][seg * 24];
        uint4* d = (uint4*)(gates + ((size_t)b * T_ + t0 + row) * G3 + seg * 24);
        d[0] = s[0]; d[1] = s[1]; d[2] = s[2];
      }
    }
    __syncthreads();
  }
}

// K2: GRU recurrence, 16 real batch rows per wg (grid=16). A-tile = 16
// distinct h rows; full D-tile used. Per-thread h state: col = tid&255,
// rows (tid>>8)*8 .. +7, fp32 registers.
__global__ __launch_bounds__(512)
__attribute__((amdgpu_waves_per_eu(2, 2)))
void rec_kernel(
    const int* __restrict__ lens, const __half* __restrict__ whh_p,
    const float* __restrict__ b_hh, const __half* __restrict__ gates,
    float* __restrict__ hfin) {
  __shared__ __align__(16) __half hT[16][264];     // h per row, A-tile layout
  __shared__ float recs2[16][769];                 // D-tile, padded stride
  __shared__ int len_s[16];
  const int tid = threadIdx.x;
  const int r0g = blockIdx.x * 16;                 // first batch row of wg
  const int l = tid & 63, w = tid >> 6;
  const int col = tid & 255;
  const int rhalf = (tid >> 8) * 8;                // rows rhalf..rhalf+7

  uint4 Bv[NFRAG];
  load_w_frag(whh_p, tid, Bv);

  const float bh0 = b_hh[col];
  const float bh1 = b_hh[256 + col];
  const float bh2 = b_hh[512 + col];

  if (tid < 16) len_s[tid] = lens[r0g + tid];
  float h[8];
#pragma unroll
  for (int i = 0; i < 8; ++i) {
    h[i] = 0.f;
    hT[rhalf + i][col] = (__half)0.f;
  }
  __syncthreads();

  int len_max = 0;
#pragma unroll
  for (int i = 0; i < 16; ++i) len_max = max(len_max, len_s[i]);

  for (int t = 0; t < len_max; ++t) {
    f32x4 acc[6];
#pragma unroll
    for (int nt = 0; nt < 6; ++nt) acc[nt] = (f32x4){0.f, 0.f, 0.f, 0.f};
#pragma unroll
    for (int kt = 0; kt < 8; ++kt) {
      f16x8 A = *(const f16x8*)&hT[l & 15][kt * 32 + ((l >> 4) & 3) * 8];
#pragma unroll
      for (int nt = 0; nt < 6; ++nt) acc[nt] = mfma16(A, Bv[nt * 8 + kt], acc[nt]);
    }
    // D[row][colD]: row = quad*4+reg (batch row), colD = w*96+nt*16+(l&15)
#pragma unroll
    for (int nt = 0; nt < 6; ++nt) {
      int colD = w * 96 + nt * 16 + (l & 15);
      int rq = ((l >> 4) & 3) * 4;
      recs2[rq + 0][colD] = acc[nt].x;
      recs2[rq + 1][colD] = acc[nt].y;
      recs2[rq + 2][colD] = acc[nt].z;
      recs2[rq + 3][colD] = acc[nt].w;
    }
    __syncthreads();
    // phase B: 8 GRU updates per thread (rows rhalf..rhalf+7, fixed col)
#pragma unroll
    for (int i = 0; i < 8; ++i) {
      int row = rhalf + i;
      if (t < len_s[row]) {
        const __half* gp = gates + ((size_t)(r0g + row) * T_ + t) * G3 + col;
        float gxz = (float)gp[0];
        float gxr = (float)gp[256];
        float gxh = (float)gp[512];
        float z = sigmoidf_(gxz + recs2[row][col] + bh0);
        float r = sigmoidf_(gxr + recs2[row][256 + col] + bh1);
        float hh = tanhf_(gxh + r * (recs2[row][512 + col] + bh2));
        h[i] = z * h[i] + (1.f - z) * hh;
        hT[row][col] = (__half)h[i];
      }
    }
    __syncthreads();
  }
#pragma unroll
  for (int i = 0; i < 8; ++i) {
    hfin[(size_t)(r0g + rhalf + i) * H_ + col] = h[i];
  }
}

// K3: logits[256 x 50001] = hfin @ emb^T, fp32 tiled GEMM (unchanged).
__global__ __launch_bounds__(256) void logits_kernel(
    const float* __restrict__ hfin, const float* __restrict__ emb,
    float* __restrict__ out) {
  __shared__ float hsT[32][64];
  __shared__ float esT[32][132];
  const int tid = threadIdx.x;
  const int tx = tid & 15, ty = tid >> 4;
  const int n0 = blockIdx.x * 128;
  const int b0 = blockIdx.y * 64;
  float acc[4][8];
#pragma unroll
  for (int i = 0; i < 4; ++i)
#pragma unroll
    for (int q = 0; q < 8; ++q) acc[i][q] = 0.f;

  for (int k0 = 0; k0 < H_; k0 += 32) {
    {
      int i = tid * 8;
      int r = i >> 5;
      int c = i & 31;
      const float* src = hfin + (size_t)(b0 + r) * H_ + k0 + c;
      float4 a0 = *(const float4*)(src);
      float4 a1 = *(const float4*)(src + 4);
      hsT[c + 0][r] = a0.x; hsT[c + 1][r] = a0.y;
      hsT[c + 2][r] = a0.z; hsT[c + 3][r] = a0.w;
      hsT[c + 4][r] = a1.x; hsT[c + 5][r] = a1.y;
      hsT[c + 6][r] = a1.z; hsT[c + 7][r] = a1.w;
    }
    {
      int r = tid >> 1;
      int c = (tid & 1) * 16;
      int n = n0 + r;
      float4 e0 = {0,0,0,0}, e1 = {0,0,0,0}, e2 = {0,0,0,0}, e3 = {0,0,0,0};
      if (n < NV) {
        const float* src = emb + (size_t)n * H_ + k0 + c;
        e0 = *(const float4*)(src);
        e1 = *(const float4*)(src + 4);
        e2 = *(const float4*)(src + 8);
        e3 = *(const float4*)(src + 12);
      }
      esT[c + 0][r] = e0.x;  esT[c + 1][r] = e0.y;
      esT[c + 2][r] = e0.z;  esT[c + 3][r] = e0.w;
      esT[c + 4][r] = e1.x;  esT[c + 5][r] = e1.y;
      esT[c + 6][r] = e1.z;  esT[c + 7][r] = e1.w;
      esT[c + 8][r] = e2.x;  esT[c + 9][r] = e2.y;
      esT[c + 10][r] = e2.z; esT[c + 11][r] = e2.w;
      esT[c + 12][r] = e3.x; esT[c + 13][r] = e3.y;
      esT[c + 14][r] = e3.z; esT[c + 15][r] = e3.w;
    }
    __syncthreads();
#pragma unroll
    for (int kk = 0; kk < 32; ++kk) {
      float4 hv = *(const float4*)&hsT[kk][ty * 4];
      float4 ea = *(const float4*)&esT[kk][tx * 8];
      float4 eb = *(const float4*)&esT[kk][tx * 8 + 4];
#define ROWFMA(i, hc)                                                     \
  acc[i][0] += hc * ea.x; acc[i][1] += hc * ea.y;                         \
  acc[i][2] += hc * ea.z; acc[i][3] += hc * ea.w;                         \
  acc[i][4] += hc * eb.x; acc[i][5] += hc * eb.y;                         \
  acc[i][6] += hc * eb.z; acc[i][7] += hc * eb.w;
      ROWFMA(0, hv.x)
      ROWFMA(1, hv.y)
      ROWFMA(2, hv.z)
      ROWFMA(3, hv.w)
#undef ROWFMA
    }
    __syncthreads();
  }
#pragma unroll
  for (int i = 0; i < 4; ++i) {
    int bb = b0 + ty * 4 + i;
    float* op = out + (size_t)bb * NV + n0 + tx * 8;
#pragma unroll
    for (int q = 0; q < 8; ++q) {
      int n = n0 + tx * 8 + q;
      if (n < NV) op[q] = acc[i][q];
    }
  }
}

extern "C" void kernel_launch(void* const* d_in, const int* in_sizes, int n_in,
                              void* d_out, int out_size, void* d_ws, size_t ws_size,
                              hipStream_t stream) {
  const int* ids = (const int*)d_in[0];
  const int* lens = (const int*)d_in[1];
  const float* emb = (const float*)d_in[2];
  const float* w_ih = (const float*)d_in[3];
  const float* w_hh = (const float*)d_in[4];
  const float* b_ih = (const float*)d_in[5];
  const float* b_hh = (const float*)d_in[6];
  float* out = (float*)d_out;

  char* ws = (char*)d_ws;
  __half* gates = (__half*)ws;                                   // 78.6 MB
  float* hfin = (float*)(ws + (size_t)B_ * T_ * G3 * sizeof(__half));
  __half* wpack = (__half*)(ws + (size_t)B_ * T_ * G3 * sizeof(__half)
                            + (size_t)B_ * H_ * sizeof(float));
  __half* wih_p = wpack;                                         // 384 KB
  __half* whh_p = wpack + WELEM;                                 // 384 KB

  pack_w<<<dim3(2 * WELEM / 256), dim3(256), 0, stream>>>(w_ih, w_hh, wpack);
  gates_kernel<<<dim3(B_), dim3(512), 0, stream>>>(ids, lens, emb, wih_p, b_ih, gates);
  rec_kernel<<<dim3(B_ / 16), dim3(512), 0, stream>>>(lens, whh_p, b_hh, gates, hfin);
  logits_kernel<<<dim3((NV + 127) / 128, B_ / 64), dim3(256), 0, stream>>>(hfin, emb, out);
}